// Round 8
// baseline (40.906 us; speedup 1.0000x reference)
//
#include <hip/hip_runtime.h>
#include <stdint.h>

#define NW 169   // 13*13 windows

typedef float f32x4 __attribute__((ext_vector_type(4)));  // nontemporal-store-compatible

__device__ __forceinline__ float qw128(float x) {
    // fake_quant(w, 128, 8): clip(round(w*128), -128, 127)/128   (round = half-to-even)
    float r = rintf(x * 128.f);
    r = fminf(fmaxf(r, -128.f), 127.f);
    return r * 0.0078125f;
}
__device__ __forceinline__ float qb16384(float x) {
    // fake_quant(b, 128*128, 32): round(b*16384)/16384 (int32 clamp unreachable here)
    return rintf(x * 16384.f) * 6.103515625e-05f;
}

__device__ __forceinline__ void quant_task(const float* __restrict__ emb,
                                           uint8_t* __restrict__ q, int task) {
    const float4* in4 = (const float4*)emb + (size_t)task * 4;
    uint32_t words[4];
#pragma unroll
    for (int t = 0; t < 4; ++t) {
        float4 f = in4[t];
        float v[4] = {f.x, f.y, f.z, f.w};
        uint32_t w = 0;
#pragma unroll
        for (int j = 0; j < 4; ++j) {
            float x = fminf(fmaxf(v[j], -1.f), 0.9921875f);
            int r = (int)rintf(x * 128.f) + 128;         // [0,255]
            w |= ((uint32_t)r & 0xFFu) << (8 * j);
        }
        words[t] = w;
    }
    ((uint4*)q)[task] = make_uint4(words[0], words[1], words[2], words[3]);
}

// Fused prep, heterogeneous grid of 256-thread blocks:
//   [0, 2048)    : quantize 2^18 x 32 emb table -> biased uint8 (16 floats/thread)
//   [2048, 3848) : zero the policy plane (nontemporal; d_out poisoned before timing)
__global__ void prep_kernel(const float* __restrict__ emb, uint8_t* __restrict__ q,
                            f32x4* __restrict__ policy) {
    int bid = blockIdx.x;
    int tid = threadIdx.x;
    if (bid >= 2048) {
        int i = (bid - 2048) * 256 + tid;                // 460800 float4 total
        f32x4 z = {0.f, 0.f, 0.f, 0.f};
        __builtin_nontemporal_store(z, &policy[i]);
        return;
    }
    quant_task(emb, q, bid * 256 + tid);                 // 524288 tasks total
}

// nnue: 1024 blocks x 256 threads, 8 boards/block, 2 boards/wave.
// All 12 gather loads issued before any accumulation -> 12 in flight per wave.
// __launch_bounds__(256,4): 4 waves/SIMD (16/CU), VGPR cap 128 - fits dv arrays, no spill.
__global__ __launch_bounds__(256, 4)
void nnue_kernel(const int* __restrict__ board,
                 const uint8_t* __restrict__ embq,
                 const float* __restrict__ w1, const float* __restrict__ b1,
                 const float* __restrict__ w2, const float* __restrict__ b2,
                 const float* __restrict__ w3, const float* __restrict__ b3,
                 float* __restrict__ vout)
{
    __shared__ float w1T[32][32], w2T[32][32], w3T[32][4];   // transposed: [k][j]
    __shared__ float b1q[32], b2q[32], b3q[4];
    // Wave-private below (slots s = wv*2+rb owned by wave wv); intra-wave LDS RAW
    // ordered by lgkmcnt -> no block barrier needed after weight staging.
    __shared__ unsigned long long ballots[8][8];
    __shared__ int hashoff[8][192];                          // idx<<5; [169,192) pad 0
    __shared__ float vlds[8][32], h1lds[8][32], h2lds[8][32];

    int tid = threadIdx.x;
    for (int i = tid; i < 1024; i += 256) {
        int j = i & 31, k = i >> 5;
        w1T[k][j] = qw128(w1[j * 32 + k]);
        w2T[k][j] = qw128(w2[j * 32 + k]);
    }
    if (tid < 96) { int k = tid & 31, j = tid >> 5; w3T[k][j] = qw128(w3[j * 32 + k]); }
    if (tid < 32) { b1q[tid] = qb16384(b1[tid]); b2q[tid] = qb16384(b2[tid]); }
    if (tid < 3)  b3q[tid] = qb16384(b3[tid]);
    __syncthreads();                                     // ONLY block-wide barrier

    int wv = tid >> 6, lane = tid & 63;
    int bbase = blockIdx.x * 8;
    int sA = wv * 2, sB = wv * 2 + 1;

    // ---- ballot + hash for this wave's 2 boards ----
#pragma unroll
    for (int rb = 0; rb < 2; ++rb) {
        int s = wv * 2 + rb;
        const int* bp = board + (size_t)(bbase + s) * 450;
#pragma unroll
        for (int t = 0; t < 8; ++t) {
            int n = t * 64 + lane;
            int cell = (n < 450) ? bp[n] : 0;
            unsigned long long m = __ballot(cell != 0);
            if (lane == 0) ballots[s][t] = m;
        }
#pragma unroll
        for (int t = 0; t < 3; ++t) {
            int w = t * 64 + lane;                       // covers [0,192)
            int wi = w / 13;
            int wj = w - wi * 13;
            int idx = 0;
#pragma unroll
            for (int c = 0; c < 2; ++c) {
#pragma unroll
                for (int i = 0; i < 3; ++i) {
                    int st = c * 225 + (min(wi, 12) + i) * 15;   // clamp row for pad lanes
                    int word = st >> 6, off = st & 63;
                    unsigned long long lo = ballots[s][word];
                    unsigned long long hi = ballots[s][word + 1];
                    // (lo>>off)|(hi<<(64-off)); double-shift avoids UB, 0 at off==0
                    unsigned long long bits = (lo >> off) | ((hi << 1) << (63 - off));
                    idx |= (int)((bits >> wj) & 7ull) << (9 * c + 3 * i);
                }
            }
            hashoff[s][w] = (w < NW) ? (idx << 5) : 0;   // pad -> row 0 (masked later)
        }
    }

    // ---- gather: issue ALL 12 loads back-to-back (12 in flight per wave) ----
    int d1 = lane & 1;
    int g = lane >> 1;
    const uint8_t* base = embq + d1 * 16;
    uint4 dva[6], dvb[6];
#pragma unroll
    for (int it = 0; it < 6; ++it) dva[it] = *(const uint4*)(base + hashoff[sA][it * 32 + g]);
#pragma unroll
    for (int it = 0; it < 6; ++it) dvb[it] = *(const uint4*)(base + hashoff[sB][it * 32 + g]);

    const uint32_t M = 0x00FF00FFu;
    uint32_t keep5 = (160 + g < NW) ? 0xFFFFFFFFu : 0u;
    int jj = lane & 31, hf = lane >> 5;

    // ================= board A (no runtime-indexed arrays: duplicated) =================
    {
        uint32_t a0lo = 0, a0hi = 0, a1lo = 0, a1hi = 0; // packed u16 pairs, +128/window bias
        uint32_t a2lo = 0, a2hi = 0, a3lo = 0, a3hi = 0; // max 169*255 = 43095 < 2^16
#pragma unroll
        for (int it = 0; it < 6; ++it) {
            uint32_t x0 = dva[it].x, x1 = dva[it].y, x2 = dva[it].z, x3 = dva[it].w;
            if (it == 5) { x0 &= keep5; x1 &= keep5; x2 &= keep5; x3 &= keep5; }
            a0lo += x0 & M; a0hi += (x0 >> 8) & M;
            a1lo += x1 & M; a1hi += (x1 >> 8) & M;
            a2lo += x2 & M; a2hi += (x2 >> 8) & M;
            a3lo += x3 & M; a3hi += (x3 >> 8) & M;
        }
#pragma unroll
        for (int off = 2; off <= 32; off <<= 1) {
            a0lo += __shfl_xor(a0lo, off); a0hi += __shfl_xor(a0hi, off);
            a1lo += __shfl_xor(a1lo, off); a1hi += __shfl_xor(a1hi, off);
            a2lo += __shfl_xor(a2lo, off); a2hi += __shfl_xor(a2hi, off);
            a3lo += __shfl_xor(a3lo, off); a3hi += __shfl_xor(a3hi, off);
        }
        if (lane < 2) {                                  // lane == d1: channels [16*d1,16*d1+16)
            uint32_t lo[4] = {a0lo, a1lo, a2lo, a3lo};
            uint32_t hi[4] = {a0hi, a1hi, a2hi, a3hi};
#pragma unroll
            for (int j = 0; j < 4; ++j) {
                int c[4];
                c[0] = (int)(lo[j] & 0xFFFFu) - 21632;   // 128*169 bias
                c[1] = (int)(hi[j] & 0xFFFFu) - 21632;
                c[2] = (int)(lo[j] >> 16)     - 21632;
                c[3] = (int)(hi[j] >> 16)     - 21632;
#pragma unroll
                for (int u = 0; u < 4; ++u) {
                    int cc = min(max(c[u], -128), 127);  // clip(v,-1,127/128) exactly
                    vlds[sA][d1 * 16 + j * 4 + u] = (float)cc * 0.0078125f;
                }
            }
        }
        float t1 = 0.f;
#pragma unroll
        for (int k2 = 0; k2 < 16; ++k2) { int k = hf * 16 + k2; t1 = fmaf(vlds[sA][k], w1T[k][jj], t1); }
        t1 += __shfl_xor(t1, 32);
        t1 += b1q[jj];
        t1 = fminf(fmaxf(t1, 0.f), 0.9921875f);
        if (lane < 32) h1lds[sA][jj] = t1;

        float t2 = 0.f;
#pragma unroll
        for (int k2 = 0; k2 < 16; ++k2) { int k = hf * 16 + k2; t2 = fmaf(h1lds[sA][k], w2T[k][jj], t2); }
        t2 += __shfl_xor(t2, 32);
        t2 += b2q[jj];
        t2 = fminf(fmaxf(t2, 0.f), 0.9921875f);
        if (lane < 32) h2lds[sA][jj] = t2;

        float t3 = 0.f;
        if (jj < 3) {
#pragma unroll
            for (int k2 = 0; k2 < 16; ++k2) { int k = hf * 16 + k2; t3 = fmaf(h2lds[sA][k], w3T[k][jj], t3); }
        }
        t3 += __shfl_xor(t3, 32);
        if (lane < 3) vout[(size_t)(bbase + sA) * 3 + lane] = t3 + b3q[lane];
    }

    // ================= board B =================
    {
        uint32_t a0lo = 0, a0hi = 0, a1lo = 0, a1hi = 0;
        uint32_t a2lo = 0, a2hi = 0, a3lo = 0, a3hi = 0;
#pragma unroll
        for (int it = 0; it < 6; ++it) {
            uint32_t x0 = dvb[it].x, x1 = dvb[it].y, x2 = dvb[it].z, x3 = dvb[it].w;
            if (it == 5) { x0 &= keep5; x1 &= keep5; x2 &= keep5; x3 &= keep5; }
            a0lo += x0 & M; a0hi += (x0 >> 8) & M;
            a1lo += x1 & M; a1hi += (x1 >> 8) & M;
            a2lo += x2 & M; a2hi += (x2 >> 8) & M;
            a3lo += x3 & M; a3hi += (x3 >> 8) & M;
        }
#pragma unroll
        for (int off = 2; off <= 32; off <<= 1) {
            a0lo += __shfl_xor(a0lo, off); a0hi += __shfl_xor(a0hi, off);
            a1lo += __shfl_xor(a1lo, off); a1hi += __shfl_xor(a1hi, off);
            a2lo += __shfl_xor(a2lo, off); a2hi += __shfl_xor(a2hi, off);
            a3lo += __shfl_xor(a3lo, off); a3hi += __shfl_xor(a3hi, off);
        }
        if (lane < 2) {
            uint32_t lo[4] = {a0lo, a1lo, a2lo, a3lo};
            uint32_t hi[4] = {a0hi, a1hi, a2hi, a3hi};
#pragma unroll
            for (int j = 0; j < 4; ++j) {
                int c[4];
                c[0] = (int)(lo[j] & 0xFFFFu) - 21632;
                c[1] = (int)(hi[j] & 0xFFFFu) - 21632;
                c[2] = (int)(lo[j] >> 16)     - 21632;
                c[3] = (int)(hi[j] >> 16)     - 21632;
#pragma unroll
                for (int u = 0; u < 4; ++u) {
                    int cc = min(max(c[u], -128), 127);
                    vlds[sB][d1 * 16 + j * 4 + u] = (float)cc * 0.0078125f;
                }
            }
        }
        float t1 = 0.f;
#pragma unroll
        for (int k2 = 0; k2 < 16; ++k2) { int k = hf * 16 + k2; t1 = fmaf(vlds[sB][k], w1T[k][jj], t1); }
        t1 += __shfl_xor(t1, 32);
        t1 += b1q[jj];
        t1 = fminf(fmaxf(t1, 0.f), 0.9921875f);
        if (lane < 32) h1lds[sB][jj] = t1;

        float t2 = 0.f;
#pragma unroll
        for (int k2 = 0; k2 < 16; ++k2) { int k = hf * 16 + k2; t2 = fmaf(h1lds[sB][k], w2T[k][jj], t2); }
        t2 += __shfl_xor(t2, 32);
        t2 += b2q[jj];
        t2 = fminf(fmaxf(t2, 0.f), 0.9921875f);
        if (lane < 32) h2lds[sB][jj] = t2;

        float t3 = 0.f;
        if (jj < 3) {
#pragma unroll
            for (int k2 = 0; k2 < 16; ++k2) { int k = hf * 16 + k2; t3 = fmaf(h2lds[sB][k], w3T[k][jj], t3); }
        }
        t3 += __shfl_xor(t3, 32);
        if (lane < 3) vout[(size_t)(bbase + sB) * 3 + lane] = t3 + b3q[lane];
    }
}

extern "C" void kernel_launch(void* const* d_in, const int* in_sizes, int n_in,
                              void* d_out, int out_size, void* d_ws, size_t ws_size,
                              hipStream_t stream) {
    const int*   board = (const int*)d_in[0];
    const float* emb   = (const float*)d_in[1];
    const float* w1    = (const float*)d_in[2];
    const float* b1    = (const float*)d_in[3];
    const float* w2    = (const float*)d_in[4];
    const float* b2    = (const float*)d_in[5];
    const float* w3    = (const float*)d_in[6];
    const float* b3    = (const float*)d_in[7];
    float* out = (float*)d_out;
    uint8_t* embq = (uint8_t*)d_ws;                      // 2^18 * 32 = 8.4 MB

    // v = out[0 : 8192*3], policy = out[24576 : 24576+1843200]
    prep_kernel<<<3848, 256, 0, stream>>>(emb, embq, (f32x4*)(out + 24576));
    nnue_kernel<<<1024, 256, 0, stream>>>(board, embq, w1, b1, w2, b2, w3, b3, out);
}